// Round 14
// baseline (65.288 us; speedup 1.0000x reference)
//
#include <hip/hip_runtime.h>

#define DEVFN __device__ __forceinline__

constexpr int B = 4, S = 2048, H = 4, DH = 16, D = 64, F = 256;
constexpr int T = B * S;        // 8192 tokens
constexpr float LOG2E = 1.44269504f;

typedef __attribute__((ext_vector_type(8))) short s16x8;
typedef __attribute__((ext_vector_type(16))) float f32x16;

DEVFN float wave_sum(float v) {
#pragma unroll
    for (int mask = 32; mask >= 1; mask >>= 1)
        v += __shfl_xor(v, mask, 64);
    return v;
}

DEVFN unsigned short f2bf(float f) {
    unsigned b = __float_as_uint(f);
    return (unsigned short)((b + 0x8000u) >> 16);
}
DEVFN unsigned cvtpk(float lo, float hi) {
    unsigned r;
    asm("v_cvt_pk_bf16_f32 %0, %1, %2" : "=v"(r) : "v"(lo), "v"(hi));
    return r;
}
DEVFN void plswap(unsigned& a, unsigned& b) {
#if __has_builtin(__builtin_amdgcn_permlane32_swap)
    typedef unsigned uv2 __attribute__((ext_vector_type(2)));
    uv2 r = __builtin_amdgcn_permlane32_swap(a, b, false, false);
    a = r[0]; b = r[1];
#else
    asm volatile("v_permlane32_swap_b32 %0, %1" : "+v"(a), "+v"(b));
#endif
}

// ---------------------------------------------------------------- kernel 1
// QKV projection, 8 tokens per block. Blocks 0..15 also build fp32 row-quad
// packed weights wo4/w14/w24 for k_post.  (verbatim from R12)
__global__ __launch_bounds__(128) void k_qkv(
    const float* __restrict__ x,
    const float* __restrict__ wq, const float* __restrict__ bq,
    const float* __restrict__ wk, const float* __restrict__ bk,
    const float* __restrict__ wv, const float* __restrict__ bv,
    const float* __restrict__ wo, const float* __restrict__ w1,
    const float* __restrict__ w2,
    unsigned short* __restrict__ Qb, unsigned short* __restrict__ Kb,
    unsigned short* __restrict__ Vtg,
    float4* __restrict__ wo4, float4* __restrict__ w14,
    float4* __restrict__ w24)
{
    __shared__ float xs[8][64];
    int tid = threadIdx.x;
    int t0 = blockIdx.x * 8;
    ((float4*)xs)[tid] = ((const float4*)(x + t0 * D))[tid];

    if (blockIdx.x < 16) {            // one-time packed weight build
        int bi = blockIdx.x;
        if (tid < 64) {               // wo4: 1024 = 16 d4 x 64 j
            int idx = bi * 64 + tid;
            int d4 = idx >> 6, j = idx & 63;
            float4 v = { wo[(4 * d4 + 0) * D + j], wo[(4 * d4 + 1) * D + j],
                         wo[(4 * d4 + 2) * D + j], wo[(4 * d4 + 3) * D + j] };
            wo4[idx] = v;
        }
#pragma unroll
        for (int e = 0; e < 2; ++e) { // w14: 4096 = 16 d4 x 256 f
            int idx = bi * 256 + e * 128 + tid;
            int d4 = idx >> 8, f = idx & 255;
            float4 v = { w1[(4 * d4 + 0) * F + f], w1[(4 * d4 + 1) * F + f],
                         w1[(4 * d4 + 2) * F + f], w1[(4 * d4 + 3) * F + f] };
            w14[idx] = v;
        }
#pragma unroll
        for (int e = 0; e < 2; ++e) { // w24: 4096 = 64 f4 x 64 j
            int idx = bi * 256 + e * 128 + tid;
            int f4 = idx >> 6, j = idx & 63;
            float4 v = { w2[(4 * f4 + 0) * D + j], w2[(4 * f4 + 1) * D + j],
                         w2[(4 * f4 + 2) * D + j], w2[(4 * f4 + 3) * D + j] };
            w24[idx] = v;
        }
    }
    __syncthreads();

    int j = tid & 63, g = tid >> 6;
    int h = j >> 4, k = j & 15;
    int wbase = h * (D * DH) + k;

    float qa[4], ka[4], va[4];
#pragma unroll
    for (int i = 0; i < 4; ++i) { qa[i] = bq[j]; ka[i] = bk[j]; va[i] = bv[j]; }

#pragma unroll 8
    for (int d = 0; d < D; ++d) {
        float wqv = wq[wbase + d * DH];
        float wkv = wk[wbase + d * DH];
        float wvv = wv[wbase + d * DH];
#pragma unroll
        for (int i = 0; i < 4; ++i) {
            float xd = xs[g * 4 + i][d];
            qa[i] = fmaf(xd, wqv, qa[i]);
            ka[i] = fmaf(xd, wkv, ka[i]);
            va[i] = fmaf(xd, wvv, va[i]);
        }
    }
    int b = t0 >> 11;
    int pair = b * H + h;
    unsigned short vv[4];
#pragma unroll
    for (int i = 0; i < 4; ++i) {
        int t = t0 + g * 4 + i;
        int s = t & (S - 1);
        int off = (pair * S + s) * DH + k;
        Qb[off] = f2bf(qa[i] * (0.25f * LOG2E));
        Kb[off] = f2bf(ka[i]);
        vv[i] = f2bf(va[i]);
    }
    int s0 = (t0 & (S - 1)) + g * 4;
    ushort4 pk = { vv[0], vv[1], vv[2], vv[3] };
    *(ushort4*)(Vtg + (size_t)(pair * DH + k) * S + s0) = pk;
}

// ---------------------------------------------------------------- kernel 2
// Full-row MFMA flash attention: block = (pair, qb). 1024 threads = 16
// waves = 4 q-groups x 4 k-groups. Loop over 128-key chunks, double-
// buffered LDS K/V; in-block fp32 merge of 4 k-group partials; writes
// final normalized A. No P buffer, no merge kernel.
__global__ __launch_bounds__(1024) void k_attn(
    const unsigned short* __restrict__ Qb, const unsigned short* __restrict__ Kb,
    const unsigned short* __restrict__ Vtg, float* __restrict__ A)
{
    union SH {
        struct {
            unsigned short Kt[2][128][16];   // 8 KB, chunk16 slot ^= key&1
            unsigned short Vt[2][16][132];   // 8.25 KB, pad 132 (bank-clean)
        } t;
        float mg[4][4][64][10];              // 40 KB: qg, kg, lane, {m,l,acc8}
    };
    __shared__ SH sh;

    int tid = threadIdx.x, lane = tid & 63;
    int w = tid >> 6;                 // 0..15
    int qg = w >> 2, kg = w & 3;
    int pair = blockIdx.x & 15;
    int qb = 15 - (blockIdx.x >> 4);  // longest first
    int nc = qb + 1;

    int qn = lane & 31, g = lane >> 5;
    int qrow = qb * 128 + qg * 32 + qn;
    int vrow = lane & 15;

    s16x8 qf = *(const s16x8*)(Qb + (size_t)(pair * S + qrow) * DH + g * 8);

    // chunk stager: all 1024 threads, 4B each for K, 4B each for V
    auto stage = [&](int c, int bi) {
        int c0 = c << 7;
        {
            int key = tid >> 3, part = tid & 7;
            unsigned v = ((const unsigned*)(Kb + ((size_t)pair * S + c0) * DH))[key * 8 + part];
            int slot = (part >> 2) ^ (key & 1);
            *(unsigned*)&sh.t.Kt[bi][key][slot * 8 + (part & 3) * 2] = v;
        }
        {
            int row = tid >> 6, col2 = tid & 63;
            unsigned v = ((const unsigned*)(Vtg + ((size_t)pair * DH + row) * S + c0))[col2];
            *(unsigned*)&sh.t.Vt[bi][row][col2 * 2] = v;
        }
    };

    stage(0, 0);

    f32x16 czero;
#pragma unroll
    for (int i = 0; i < 16; ++i) czero[i] = 0.f;
    f32x16 acc = czero;
    float mrun = -1e30f, lsum = 0.f;

    for (int c = 0; c < nc; ++c) {
        __syncthreads();                       // buf[c&1] ready; prev reads done
        if (c + 1 < nc) stage(c + 1, (c + 1) & 1);
        bool active = (c < qb) || (kg <= qg);
        if (active) {
            int bi = c & 1;
            int krow = kg * 32 + qn;
            s16x8 kf = *(const s16x8*)&sh.t.Kt[bi][krow][(g ^ (krow & 1)) * 8];
            f32x16 sc = __builtin_amdgcn_mfma_f32_32x32x16_bf16(kf, qf, czero, 0, 0, 0);
            if (c == qb && kg == qg) {         // diagonal tile: mask m <= qn
#pragma unroll
                for (int r = 0; r < 16; ++r) {
                    int m = (r & 3) + 8 * (r >> 2) + 4 * g;
                    sc[r] = (m <= qn) ? sc[r] : -1e30f;
                }
            }
            float t0a = fmaxf(fmaxf(sc[0], sc[1]), sc[2]);
            float t1a = fmaxf(fmaxf(sc[3], sc[4]), sc[5]);
            float t2a = fmaxf(fmaxf(sc[6], sc[7]), sc[8]);
            float t3a = fmaxf(fmaxf(sc[9], sc[10]), sc[11]);
            float t4a = fmaxf(fmaxf(sc[12], sc[13]), sc[14]);
            float tm = fmaxf(fmaxf(fmaxf(t0a, t1a), fmaxf(t2a, t3a)),
                             fmaxf(t4a, sc[15]));
            tm = fmaxf(tm, __shfl_xor(tm, 32, 64));
            float mnew = fmaxf(mrun, tm);
            float scale = exp2f(mrun - mnew);
            mrun = mnew;
            float p[16];
            float ts0 = 0.f, ts1 = 0.f, ts2 = 0.f, ts3 = 0.f;
#pragma unroll
            for (int r = 0; r < 16; r += 4) {
                p[r]     = exp2f(sc[r] - mnew);     ts0 += p[r];
                p[r + 1] = exp2f(sc[r + 1] - mnew); ts1 += p[r + 1];
                p[r + 2] = exp2f(sc[r + 2] - mnew); ts2 += p[r + 2];
                p[r + 3] = exp2f(sc[r + 3] - mnew); ts3 += p[r + 3];
            }
            float ts = (ts0 + ts1) + (ts2 + ts3);
            ts += __shfl_xor(ts, 32, 64);
            lsum = fmaf(lsum, scale, ts);
#pragma unroll
            for (int r = 0; r < 8; ++r) acc[r] *= scale;

            unsigned a0 = cvtpk(p[0],  p[1]);
            unsigned a1 = cvtpk(p[2],  p[3]);
            unsigned a2 = cvtpk(p[4],  p[5]);
            unsigned a3 = cvtpk(p[6],  p[7]);
            unsigned b0 = cvtpk(p[8],  p[9]);
            unsigned b1 = cvtpk(p[10], p[11]);
            unsigned b2 = cvtpk(p[12], p[13]);
            unsigned b3 = cvtpk(p[14], p[15]);
            plswap(a0, a2);
            plswap(a1, a3);
            plswap(b0, b2);
            plswap(b1, b3);
            union UU { unsigned u[4]; s16x8 v; };
            UU pf0, pf1;
            pf0.u[0] = a0; pf0.u[1] = a1; pf0.u[2] = a2; pf0.u[3] = a3;
            pf1.u[0] = b0; pf1.u[1] = b1; pf1.u[2] = b2; pf1.u[3] = b3;

            s16x8 vf0 = *(const s16x8*)&sh.t.Vt[bi][vrow][kg * 32 + g * 8];
            s16x8 vf1 = *(const s16x8*)&sh.t.Vt[bi][vrow][kg * 32 + 16 + g * 8];
            acc = __builtin_amdgcn_mfma_f32_32x32x16_bf16(vf0, pf0.v, acc, 0, 0, 0);
            acc = __builtin_amdgcn_mfma_f32_32x32x16_bf16(vf1, pf1.v, acc, 0, 0, 0);
        }
    }

    __syncthreads();                  // tile bufs dead; reuse LDS as mg
    {
        float* pp = &sh.mg[qg][kg][lane][0];
        pp[0] = mrun; pp[1] = lsum;
#pragma unroll
        for (int j = 0; j < 8; ++j) pp[2 + j] = acc[j];
    }
    __syncthreads();

    if (kg == 0) {
        float M = mrun, L = lsum;
        float a[8];
#pragma unroll
        for (int j = 0; j < 8; ++j) a[j] = acc[j];
#pragma unroll
        for (int kk = 1; kk < 4; ++kk) {
            const float* qq = &sh.mg[qg][kk][lane][0];
            float m2 = qq[0], l2 = qq[1];
            float Mn = fmaxf(M, m2);
            float e1 = exp2f(M - Mn), e2 = exp2f(m2 - Mn);
            L = L * e1 + l2 * e2;
#pragma unroll
            for (int j = 0; j < 8; ++j)
                a[j] = a[j] * e1 + qq[2 + j] * e2;
            M = Mn;
        }
        float inv = 1.f / L;
        int b = pair >> 2, h = pair & 3;
        float* Ap = A + (size_t)(b * S + qrow) * D + h * 16;
        float4 o0 = { a[0] * inv, a[1] * inv, a[2] * inv, a[3] * inv };
        float4 o1 = { a[4] * inv, a[5] * inv, a[6] * inv, a[7] * inv };
        *(float4*)(Ap + 4 * g)     = o0;   // dims {4g..4g+3}
        *(float4*)(Ap + 8 + 4 * g) = o1;   // dims {8+4g..8+4g+3}
    }
}

// ---------------------------------------------------------------- kernel 3
// Fused post: A-load + oproj + LN1 + FFN + LN2. 8 tokens / 256 threads.
__global__ __launch_bounds__(256) void k_post(
    const float* __restrict__ Aall, const float* __restrict__ x,
    const float4* __restrict__ wo4, const float* __restrict__ bo,
    const float* __restrict__ g1, const float* __restrict__ bb1,
    const float4* __restrict__ w14, const float* __restrict__ b1,
    const float4* __restrict__ w24, const float* __restrict__ b2,
    const float* __restrict__ g2, const float* __restrict__ bb2,
    float* __restrict__ out)
{
    __shared__ float As[8][68];      // attention out (head-concat)
    __shared__ float R1s[8][68];     // post-LN1
    __shared__ float hht[8][260];    // ffn hidden, token-major

    int tid = threadIdx.x;
    int t0 = blockIdx.x * 8;

    // ---- phase 1: load A -> As
    {
        int token = tid >> 5, d2 = tid & 31;
        float2 v = *(const float2*)(Aall + (size_t)(t0 + token) * D + d2 * 2);
        *(float2*)&As[token][d2 * 2] = v;
    }
    __syncthreads();

    // ---- phase 2: out-proj + residual + LN1 -> R1s
    {
        int g = tid >> 6, j = tid & 63;      // tokens 2g, 2g+1
        float o0 = bo[j] + x[(t0 + 2 * g + 0) * D + j];
        float o1 = bo[j] + x[(t0 + 2 * g + 1) * D + j];
#pragma unroll
        for (int d4 = 0; d4 < 16; ++d4) {
            float4 wv = wo4[d4 * 64 + j];
            float4 a0v = *(const float4*)&As[2 * g + 0][4 * d4];
            float4 a1v = *(const float4*)&As[2 * g + 1][4 * d4];
            o0 = fmaf(a0v.x, wv.x, o0); o0 = fmaf(a0v.y, wv.y, o0);
            o0 = fmaf(a0v.z, wv.z, o0); o0 = fmaf(a0v.w, wv.w, o0);
            o1 = fmaf(a1v.x, wv.x, o1); o1 = fmaf(a1v.y, wv.y, o1);
            o1 = fmaf(a1v.z, wv.z, o1); o1 = fmaf(a1v.w, wv.w, o1);
        }
        float gj = g1[j], bj = bb1[j];
        {
            float mu = wave_sum(o0) * (1.f / 64.f);
            float dif = o0 - mu;
            float var = wave_sum(dif * dif) * (1.f / 64.f);
            R1s[2 * g + 0][j] = dif * rsqrtf(var + 1e-5f) * gj + bj;
        }
        {
            float mu = wave_sum(o1) * (1.f / 64.f);
            float dif = o1 - mu;
            float var = wave_sum(dif * dif) * (1.f / 64.f);
            R1s[2 * g + 1][j] = dif * rsqrtf(var + 1e-5f) * gj + bj;
        }
    }
    __syncthreads();

    // ---- phase 3: FFN stage 1 (hidden f = tid, 8 tokens) -> hht
    {
        int f = tid;
        float h[8];
#pragma unroll
        for (int t = 0; t < 8; ++t) h[t] = b1[f];
#pragma unroll
        for (int d4 = 0; d4 < 16; ++d4) {
            float4 wv = w14[d4 * 256 + f];
#pragma unroll
            for (int t = 0; t < 8; ++t) {
                float4 xv = *(const float4*)&R1s[t][4 * d4];
                h[t] = fmaf(xv.x, wv.x, h[t]); h[t] = fmaf(xv.y, wv.y, h[t]);
                h[t] = fmaf(xv.z, wv.z, h[t]); h[t] = fmaf(xv.w, wv.w, h[t]);
            }
        }
#pragma unroll
        for (int t = 0; t < 8; ++t)
            hht[t][f] = fmaxf(h[t], 0.f);
    }
    __syncthreads();

    // ---- phase 4: FFN stage 2 + residual + LN2 -> out
    {
        int g = tid >> 6, j = tid & 63;      // tokens 2g, 2g+1
        float y0 = b2[j] + R1s[2 * g + 0][j];
        float y1 = b2[j] + R1s[2 * g + 1][j];
#pragma unroll
        for (int f4 = 0; f4 < 64; ++f4) {
            float4 wv = w24[f4 * 64 + j];
            float4 h0 = *(const float4*)&hht[2 * g + 0][4 * f4];
            float4 h1 = *(const float4*)&hht[2 * g + 1][4 * f4];
            y0 = fmaf(h0.x, wv.x, y0); y0 = fmaf(h0.y, wv.y, y0);
            y0 = fmaf(h0.z, wv.z, y0); y0 = fmaf(h0.w, wv.w, y0);
            y1 = fmaf(h1.x, wv.x, y1); y1 = fmaf(h1.y, wv.y, y1);
            y1 = fmaf(h1.z, wv.z, y1); y1 = fmaf(h1.w, wv.w, y1);
        }
        float gj = g2[j], bj = bb2[j];
        {
            float mu = wave_sum(y0) * (1.f / 64.f);
            float dif = y0 - mu;
            float var = wave_sum(dif * dif) * (1.f / 64.f);
            out[(t0 + 2 * g + 0) * D + j] = dif * rsqrtf(var + 1e-5f) * gj + bj;
        }
        {
            float mu = wave_sum(y1) * (1.f / 64.f);
            float dif = y1 - mu;
            float var = wave_sum(dif * dif) * (1.f / 64.f);
            out[(t0 + 2 * g + 1) * D + j] = dif * rsqrtf(var + 1e-5f) * gj + bj;
        }
    }
}

// ----------------------------------------------------------------
extern "C" void kernel_launch(void* const* d_in, const int* in_sizes, int n_in,
                              void* d_out, int out_size, void* d_ws, size_t ws_size,
                              hipStream_t stream)
{
    const float* x   = (const float*)d_in[0];
    const float* wq  = (const float*)d_in[1];
    const float* bq  = (const float*)d_in[2];
    const float* wk  = (const float*)d_in[3];
    const float* bk  = (const float*)d_in[4];
    const float* wv  = (const float*)d_in[5];
    const float* bv  = (const float*)d_in[6];
    const float* wo  = (const float*)d_in[7];
    const float* bo  = (const float*)d_in[8];
    const float* g1  = (const float*)d_in[9];
    const float* be1 = (const float*)d_in[10];
    const float* w1  = (const float*)d_in[11];
    const float* b1  = (const float*)d_in[12];
    const float* w2  = (const float*)d_in[13];
    const float* b2  = (const float*)d_in[14];
    const float* g2  = (const float*)d_in[15];
    const float* be2 = (const float*)d_in[16];

    char* base = (char*)d_ws;
    unsigned short* Qb  = (unsigned short*)base;                  // 1 MB
    unsigned short* Kb  = (unsigned short*)(base + (1u << 20));   // 1 MB
    unsigned short* Vtg = (unsigned short*)(base + (2u << 20));   // 1 MB
    float*          A   = (float*)(base + (3u << 20));            // 2 MB
    float4*         wo4 = (float4*)(base + (6u << 20));           // 16 KB
    float4*         w14 = (float4*)(base + (6u << 20) + 0x10000); // 64 KB
    float4*         w24 = (float4*)(base + (6u << 20) + 0x20000); // 64 KB

    k_qkv <<<T / 8, 128, 0, stream>>>(x, wq, bq, wk, bk, wv, bv,
                                      wo, w1, w2, Qb, Kb, Vtg,
                                      wo4, w14, w24);
    k_attn<<<256, 1024, 0, stream>>>(Qb, Kb, Vtg, A);
    k_post<<<T / 8, 256, 0, stream>>>(A, x, wo4, bo, g1, be1,
                                      w14, b1, w24, b2, g2, be2,
                                      (float*)d_out);
}

// Round 15
// 56.936 us; speedup vs baseline: 1.1467x; 1.1467x over previous
//
#include <hip/hip_runtime.h>

#define DEVFN __device__ __forceinline__

constexpr int B = 4, S = 2048, H = 4, DH = 16, D = 64, F = 256;
constexpr int T = B * S;        // 8192 tokens
constexpr int PAIRS = B * H;    // 16
constexpr int CPP = 72;         // chunk-blocks per pair = sum_{qb=0..15}(qb/2+1)
constexpr int NZ = PAIRS * CPP; // 1152 attention partial blocks
constexpr int PSTRIDE = 1280;   // floats: 128 m + 128 l + 128x16 bf16 acc
constexpr float LOG2E = 1.44269504f;

typedef __attribute__((ext_vector_type(8))) short s16x8;
typedef __attribute__((ext_vector_type(16))) float f32x16;

DEVFN float wave_sum(float v) {
#pragma unroll
    for (int mask = 32; mask >= 1; mask >>= 1)
        v += __shfl_xor(v, mask, 64);
    return v;
}

DEVFN unsigned short f2bf(float f) {
    unsigned b = __float_as_uint(f);
    return (unsigned short)((b + 0x8000u) >> 16);
}
DEVFN unsigned pack_bf2(float lo, float hi) {
    unsigned a = __float_as_uint(lo), b = __float_as_uint(hi);
    return ((a + 0x8000u) >> 16) | ((b + 0x8000u) & 0xffff0000u);
}
DEVFN unsigned cvtpk(float lo, float hi) {
    unsigned r;
    asm("v_cvt_pk_bf16_f32 %0, %1, %2" : "=v"(r) : "v"(lo), "v"(hi));
    return r;
}
DEVFN void plswap(unsigned& a, unsigned& b) {
#if __has_builtin(__builtin_amdgcn_permlane32_swap)
    typedef unsigned uv2 __attribute__((ext_vector_type(2)));
    uv2 r = __builtin_amdgcn_permlane32_swap(a, b, false, false);
    a = r[0]; b = r[1];
#else
    asm volatile("v_permlane32_swap_b32 %0, %1" : "+v"(a), "+v"(b));
#endif
}

// ---------------------------------------------------------------- kernel 1
// QKV projection, 32 tokens per block (256 thr, grid 256). x staged
// TRANSPOSED in LDS (padded, aligned) -> b128 broadcast reads; weight-load
// instruction count halved vs 8-token version. Blocks 0..15 also build
// fp32 row-quad packed weights wo4/w14/w24 for k_post.
__global__ __launch_bounds__(256) void k_qkv(
    const float* __restrict__ x,
    const float* __restrict__ wq, const float* __restrict__ bq,
    const float* __restrict__ wk, const float* __restrict__ bk,
    const float* __restrict__ wv, const float* __restrict__ bv,
    const float* __restrict__ wo, const float* __restrict__ w1,
    const float* __restrict__ w2,
    unsigned short* __restrict__ Qb, unsigned short* __restrict__ Kb,
    unsigned short* __restrict__ Vtg,
    float4* __restrict__ wo4, float4* __restrict__ w14,
    float4* __restrict__ w24)
{
    __shared__ float xst[64][36];    // transposed x tile, 144B row (aligned)
    int tid = threadIdx.x;
    int t0 = blockIdx.x * 32;

    // coalesced load of x, transposed store to LDS
    int token = tid >> 3, dseg = tid & 7;
    float4 xa = *(const float4*)(x + (size_t)(t0 + token) * D + dseg * 8);
    float4 xb = *(const float4*)(x + (size_t)(t0 + token) * D + dseg * 8 + 4);

    if (blockIdx.x < 16) {            // one-time packed weight build
        int bi = blockIdx.x;
        if (tid < 64) {               // wo4: 1024 = 16 d4 x 64 j
            int idx = bi * 64 + tid;
            int d4 = idx >> 6, j = idx & 63;
            float4 v = { wo[(4 * d4 + 0) * D + j], wo[(4 * d4 + 1) * D + j],
                         wo[(4 * d4 + 2) * D + j], wo[(4 * d4 + 3) * D + j] };
            wo4[idx] = v;
        }
        {                             // w14: 4096 = 16 d4 x 256 f
            int idx = bi * 256 + tid;
            int d4 = idx >> 8, f = idx & 255;
            float4 v = { w1[(4 * d4 + 0) * F + f], w1[(4 * d4 + 1) * F + f],
                         w1[(4 * d4 + 2) * F + f], w1[(4 * d4 + 3) * F + f] };
            w14[idx] = v;
        }
        {                             // w24: 4096 = 64 f4 x 64 j
            int idx = bi * 256 + tid;
            int f4 = idx >> 6, j = idx & 63;
            float4 v = { w2[(4 * f4 + 0) * D + j], w2[(4 * f4 + 1) * D + j],
                         w2[(4 * f4 + 2) * D + j], w2[(4 * f4 + 3) * D + j] };
            w24[idx] = v;
        }
    }

    xst[dseg * 8 + 0][token] = xa.x;
    xst[dseg * 8 + 1][token] = xa.y;
    xst[dseg * 8 + 2][token] = xa.z;
    xst[dseg * 8 + 3][token] = xa.w;
    xst[dseg * 8 + 4][token] = xb.x;
    xst[dseg * 8 + 5][token] = xb.y;
    xst[dseg * 8 + 6][token] = xb.z;
    xst[dseg * 8 + 7][token] = xb.w;
    __syncthreads();

    int j = tid & 63, g = tid >> 6;   // g in 0..3, 8 tokens each
    int h = j >> 4, k = j & 15;
    int wbase = h * (D * DH) + k;

    float qa[8], ka[8], va[8];
#pragma unroll
    for (int i = 0; i < 8; ++i) { qa[i] = bq[j]; ka[i] = bk[j]; va[i] = bv[j]; }

#pragma unroll 4
    for (int d = 0; d < D; ++d) {
        float wqv = wq[wbase + d * DH];
        float wkv = wk[wbase + d * DH];
        float wvv = wv[wbase + d * DH];
        float4 xv0 = *(const float4*)&xst[d][g * 8];
        float4 xv1 = *(const float4*)&xst[d][g * 8 + 4];
        float xe[8] = { xv0.x, xv0.y, xv0.z, xv0.w, xv1.x, xv1.y, xv1.z, xv1.w };
#pragma unroll
        for (int i = 0; i < 8; ++i) {
            qa[i] = fmaf(xe[i], wqv, qa[i]);
            ka[i] = fmaf(xe[i], wkv, ka[i]);
            va[i] = fmaf(xe[i], wvv, va[i]);
        }
    }
    int b = t0 >> 11;
    int pair = b * H + h;
    unsigned short vv[8];
#pragma unroll
    for (int i = 0; i < 8; ++i) {
        int t = t0 + g * 8 + i;
        int s = t & (S - 1);
        int off = (pair * S + s) * DH + k;
        Qb[off] = f2bf(qa[i] * (0.25f * LOG2E));
        Kb[off] = f2bf(ka[i]);
        vv[i] = f2bf(va[i]);
    }
    int s0 = (t0 & (S - 1)) + g * 8;
    uint4 pk;
    pk.x = (unsigned)vv[0] | ((unsigned)vv[1] << 16);
    pk.y = (unsigned)vv[2] | ((unsigned)vv[3] << 16);
    pk.z = (unsigned)vv[4] | ((unsigned)vv[5] << 16);
    pk.w = (unsigned)vv[6] | ((unsigned)vv[7] << 16);
    *(uint4*)(Vtg + (size_t)(pair * DH + k) * S + s0) = pk;
}

// ---------------------------------------------------------------- kernel 2
// MFMA flash attention partial (R10-R12 verbatim) + XCD-bijective block
// swizzle (1152 = 8 x 144): each XCD's L2 sees ~2 pairs' K/V.
__global__ __launch_bounds__(256) void k_attn_part(
    const unsigned short* __restrict__ Qb, const unsigned short* __restrict__ Kb,
    const unsigned short* __restrict__ Vtg, float* __restrict__ P)
{
    __shared__ unsigned short Kt[256][16];   // chunk16 slot ^= key&1
    __shared__ unsigned short Vt[16][264];   // padded rows

    int tid = threadIdx.x, lane = tid & 63, w = tid >> 6;

    int bid0 = blockIdx.x;
    int z = (bid0 & 7) * 144 + (bid0 >> 3);  // XCD-bijective swizzle
    int pair = z / CPP;
    int rem = z - pair * CPP;
    int qb = 0, cum = 0;
    while (cum + (qb >> 1) + 1 <= rem) { cum += (qb >> 1) + 1; ++qb; }
    int kc = rem - cum;
    int kbase = kc << 8;
    int qbase = qb << 7;

    {
        const uint4* src = (const uint4*)(Kb + (size_t)(pair * S + kbase + tid) * DH);
        uint4 lo = src[0], hi = src[1];
        *(uint4*)&Kt[tid][(tid & 1) * 8] = lo;
        *(uint4*)&Kt[tid][((tid & 1) ^ 1) * 8] = hi;
        int r = tid >> 4, cc = tid & 15;
        const uint4* vs = (const uint4*)(Vtg + (size_t)(pair * DH + r) * S + kbase + cc * 16);
        uint4 v0 = vs[0], v1 = vs[1];
        *(uint4*)&Vt[r][cc * 16] = v0;
        *(uint4*)&Vt[r][cc * 16 + 8] = v1;
    }
    __syncthreads();

    int qn = lane & 31, g = lane >> 5;
    int q0w = qbase + w * 32;
    int qg = q0w + qn;
    int vrow = lane & 15;

    s16x8 qf = *(const s16x8*)(Qb + (size_t)(pair * S + qg) * DH + g * 8);

    f32x16 czero;
#pragma unroll
    for (int i = 0; i < 16; ++i) czero[i] = 0.f;
    f32x16 acc = czero;
    float mrun = -1e30f, lsum = 0.f;

    int nt = ((q0w + 31 - kbase) >> 5) + 1;
    if (nt > 8) nt = 8;

    int krow0 = qn;
    s16x8 kf = *(const s16x8*)&Kt[krow0][(g ^ (krow0 & 1)) * 8];

    for (int t = 0; t < nt; ++t) {
        int kl = t * 32;
        s16x8 vf0 = *(const s16x8*)&Vt[vrow][kl + g * 8];
        s16x8 vf1 = *(const s16x8*)&Vt[vrow][kl + 16 + g * 8];
        int tn = (t + 1 < nt) ? (t + 1) : t;
        int krown = tn * 32 + qn;
        s16x8 kfn = *(const s16x8*)&Kt[krown][(g ^ (krown & 1)) * 8];

        f32x16 sc = __builtin_amdgcn_mfma_f32_32x32x16_bf16(kf, qf, czero, 0, 0, 0);
        if (t == nt - 1) {                        // diagonal tile: causal mask
            int qml = qg - (kbase + kl);
#pragma unroll
            for (int r = 0; r < 16; ++r) {
                int m = (r & 3) + 8 * (r >> 2) + 4 * g;
                sc[r] = (m <= qml) ? sc[r] : -1e30f;
            }
        }
        float t0a = fmaxf(fmaxf(sc[0], sc[1]), sc[2]);
        float t1a = fmaxf(fmaxf(sc[3], sc[4]), sc[5]);
        float t2a = fmaxf(fmaxf(sc[6], sc[7]), sc[8]);
        float t3a = fmaxf(fmaxf(sc[9], sc[10]), sc[11]);
        float t4a = fmaxf(fmaxf(sc[12], sc[13]), sc[14]);
        float tm = fmaxf(fmaxf(fmaxf(t0a, t1a), fmaxf(t2a, t3a)),
                         fmaxf(t4a, sc[15]));
        tm = fmaxf(tm, __shfl_xor(tm, 32, 64));
        float mnew = fmaxf(mrun, tm);
        float scale = exp2f(mrun - mnew);
        mrun = mnew;
        float p[16];
        float ts0 = 0.f, ts1 = 0.f, ts2 = 0.f, ts3 = 0.f;
#pragma unroll
        for (int r = 0; r < 16; r += 4) {
            p[r]     = exp2f(sc[r] - mnew);     ts0 += p[r];
            p[r + 1] = exp2f(sc[r + 1] - mnew); ts1 += p[r + 1];
            p[r + 2] = exp2f(sc[r + 2] - mnew); ts2 += p[r + 2];
            p[r + 3] = exp2f(sc[r + 3] - mnew); ts3 += p[r + 3];
        }
        float ts = (ts0 + ts1) + (ts2 + ts3);
        ts += __shfl_xor(ts, 32, 64);
        lsum = fmaf(lsum, scale, ts);
#pragma unroll
        for (int r = 0; r < 8; ++r) acc[r] *= scale;

        unsigned a0 = cvtpk(p[0],  p[1]);
        unsigned a1 = cvtpk(p[2],  p[3]);
        unsigned a2 = cvtpk(p[4],  p[5]);
        unsigned a3 = cvtpk(p[6],  p[7]);
        unsigned b0 = cvtpk(p[8],  p[9]);
        unsigned b1 = cvtpk(p[10], p[11]);
        unsigned b2 = cvtpk(p[12], p[13]);
        unsigned b3 = cvtpk(p[14], p[15]);
        plswap(a0, a2);
        plswap(a1, a3);
        plswap(b0, b2);
        plswap(b1, b3);
        union UU { unsigned u[4]; s16x8 v; };
        UU pf0, pf1;
        pf0.u[0] = a0; pf0.u[1] = a1; pf0.u[2] = a2; pf0.u[3] = a3;
        pf1.u[0] = b0; pf1.u[1] = b1; pf1.u[2] = b2; pf1.u[3] = b3;

        acc = __builtin_amdgcn_mfma_f32_32x32x16_bf16(vf0, pf0.v, acc, 0, 0, 0);
        acc = __builtin_amdgcn_mfma_f32_32x32x16_bf16(vf1, pf1.v, acc, 0, 0, 0);
        kf = kfn;
    }

    float* base = P + (size_t)z * PSTRIDE;
    if (lane < 32) {
        base[w * 32 + qn] = mrun;            // log2-domain max
        base[128 + w * 32 + qn] = lsum;
    }
    uint2 cA, cB;
    cA.x = pack_bf2(acc[0], acc[1]); cA.y = pack_bf2(acc[2], acc[3]);
    cB.x = pack_bf2(acc[4], acc[5]); cB.y = pack_bf2(acc[6], acc[7]);
    unsigned short* pa = (unsigned short*)(base + 256);
    *(uint2*)&pa[(w * 32 + qn) * 16 + 4 * g] = cA;
    *(uint2*)&pa[(w * 32 + qn) * 16 + 8 + 4 * g] = cB;
}

// ---------------------------------------------------------------- kernel 3
// Fused post (Round-11 60.78us version, verbatim): merge + oproj + LN1 +
// FFN + LN2. 16 tokens / 512 threads. fp32 row-quad weights.
__global__ __launch_bounds__(512) void k_post(
    const float* __restrict__ P, const float* __restrict__ x,
    const float4* __restrict__ wo4, const float* __restrict__ bo,
    const float* __restrict__ g1, const float* __restrict__ bb1,
    const float4* __restrict__ w14, const float* __restrict__ b1,
    const float4* __restrict__ w24, const float* __restrict__ b2,
    const float* __restrict__ g2, const float* __restrict__ bb2,
    float* __restrict__ out)
{
    __shared__ float As[16][68];     // merged attention out (head-concat)
    __shared__ float R1s[16][68];    // post-LN1
    __shared__ float hht[16][260];   // ffn hidden, token-major

    int tid = threadIdx.x;
    int t0 = blockIdx.x * 16;
    int b = t0 >> 11;
    int sbase = t0 & (S - 1);
    int qb = sbase >> 7;
    int nc = (qb >> 1) + 1;
    int cum = 0;
#pragma unroll
    for (int i = 0; i < 16; ++i) cum += (i < qb) ? ((i >> 1) + 1) : 0;

    // ---- phase 1: merge split-K partials (parallel prefetch) -> As
    {
        int pi = tid >> 3;           // 0..63 = (h, sl)
        int h = pi >> 4, sl = pi & 15;
        int dq = tid & 7;            // dims 2dq, 2dq+1
        int pair = b * H + h;
        int q = (sbase & 127) + sl;
        const float* base0 = P + ((size_t)pair * CPP + cum) * PSTRIDE;

        float mv[8], sv[8]; unsigned uv[8];
#pragma unroll
        for (int c = 0; c < 8; ++c) {
            int cc = (c < nc) ? c : (nc - 1);
            const float* bc = base0 + cc * PSTRIDE;
            float m_ = bc[q];
            float s_ = bc[128 + q];
            unsigned u_ = *(const unsigned*)((const unsigned short*)(bc + 256) + q * 16 + dq * 2);
            bool valid = (c < nc);
            mv[c] = valid ? m_ : -1e30f;
            sv[c] = valid ? s_ : 0.f;
            uv[c] = valid ? u_ : 0u;
        }
        float M = fmaxf(fmaxf(fmaxf(mv[0], mv[1]), fmaxf(mv[2], mv[3])),
                        fmaxf(fmaxf(mv[4], mv[5]), fmaxf(mv[6], mv[7])));
        float Sm = 0.f, a0 = 0.f, a1 = 0.f;
#pragma unroll
        for (int c = 0; c < 8; ++c) {
            float e = exp2f(mv[c] - M);
            Sm = fmaf(sv[c], e, Sm);
            a0 = fmaf(__uint_as_float(uv[c] << 16), e, a0);
            a1 = fmaf(__uint_as_float(uv[c] & 0xffff0000u), e, a1);
        }
        float inv = 1.f / Sm;
        float2 wv = { a0 * inv, a1 * inv };
        *(float2*)&As[sl][h * 16 + dq * 2] = wv;
    }
    __syncthreads();

    // ---- phase 2: out-proj + residual + LN1 -> R1s
    {
        int g = tid >> 6, j = tid & 63;      // tokens 2g, 2g+1
        float o0 = bo[j] + x[(t0 + 2 * g + 0) * D + j];
        float o1 = bo[j] + x[(t0 + 2 * g + 1) * D + j];
#pragma unroll
        for (int d4 = 0; d4 < 16; ++d4) {
            float4 wv = wo4[d4 * 64 + j];
            float4 a0v = *(const float4*)&As[2 * g + 0][4 * d4];
            float4 a1v = *(const float4*)&As[2 * g + 1][4 * d4];
            o0 = fmaf(a0v.x, wv.x, o0); o0 = fmaf(a0v.y, wv.y, o0);
            o0 = fmaf(a0v.z, wv.z, o0); o0 = fmaf(a0v.w, wv.w, o0);
            o1 = fmaf(a1v.x, wv.x, o1); o1 = fmaf(a1v.y, wv.y, o1);
            o1 = fmaf(a1v.z, wv.z, o1); o1 = fmaf(a1v.w, wv.w, o1);
        }
        float gj = g1[j], bj = bb1[j];
        {
            float mu = wave_sum(o0) * (1.f / 64.f);
            float dif = o0 - mu;
            float var = wave_sum(dif * dif) * (1.f / 64.f);
            R1s[2 * g + 0][j] = dif * rsqrtf(var + 1e-5f) * gj + bj;
        }
        {
            float mu = wave_sum(o1) * (1.f / 64.f);
            float dif = o1 - mu;
            float var = wave_sum(dif * dif) * (1.f / 64.f);
            R1s[2 * g + 1][j] = dif * rsqrtf(var + 1e-5f) * gj + bj;
        }
    }
    __syncthreads();

    // ---- phase 3: FFN stage 1 (hidden) -> hht (token-major)
    {
        int f = tid & 255, half = tid >> 8;
        float h[8];
#pragma unroll
        for (int t = 0; t < 8; ++t) h[t] = b1[f];
#pragma unroll
        for (int d4 = 0; d4 < 16; ++d4) {
            float4 wv = w14[d4 * 256 + f];
#pragma unroll
            for (int t = 0; t < 8; ++t) {
                float4 xv = *(const float4*)&R1s[half * 8 + t][4 * d4];
                h[t] = fmaf(xv.x, wv.x, h[t]); h[t] = fmaf(xv.y, wv.y, h[t]);
                h[t] = fmaf(xv.z, wv.z, h[t]); h[t] = fmaf(xv.w, wv.w, h[t]);
            }
        }
#pragma unroll
        for (int t = 0; t < 8; ++t)
            hht[half * 8 + t][f] = fmaxf(h[t], 0.f);
    }
    __syncthreads();

    // ---- phase 4: FFN stage 2 + residual + LN2 -> out
    {
        int g = tid >> 6, j = tid & 63;
        float y0 = b2[j] + R1s[2 * g + 0][j];
        float y1 = b2[j] + R1s[2 * g + 1][j];
#pragma unroll
        for (int f4 = 0; f4 < 64; ++f4) {
            float4 wv = w24[f4 * 64 + j];
            float4 h0 = *(const float4*)&hht[2 * g + 0][4 * f4];
            float4 h1 = *(const float4*)&hht[2 * g + 1][4 * f4];
            y0 = fmaf(h0.x, wv.x, y0); y0 = fmaf(h0.y, wv.y, y0);
            y0 = fmaf(h0.z, wv.z, y0); y0 = fmaf(h0.w, wv.w, y0);
            y1 = fmaf(h1.x, wv.x, y1); y1 = fmaf(h1.y, wv.y, y1);
            y1 = fmaf(h1.z, wv.z, y1); y1 = fmaf(h1.w, wv.w, y1);
        }
        float gj = g2[j], bj = bb2[j];
        {
            float mu = wave_sum(y0) * (1.f / 64.f);
            float dif = y0 - mu;
            float var = wave_sum(dif * dif) * (1.f / 64.f);
            out[(t0 + 2 * g + 0) * D + j] = dif * rsqrtf(var + 1e-5f) * gj + bj;
        }
        {
            float mu = wave_sum(y1) * (1.f / 64.f);
            float dif = y1 - mu;
            float var = wave_sum(dif * dif) * (1.f / 64.f);
            out[(t0 + 2 * g + 1) * D + j] = dif * rsqrtf(var + 1e-5f) * gj + bj;
        }
    }
}

// ----------------------------------------------------------------
extern "C" void kernel_launch(void* const* d_in, const int* in_sizes, int n_in,
                              void* d_out, int out_size, void* d_ws, size_t ws_size,
                              hipStream_t stream)
{
    const float* x   = (const float*)d_in[0];
    const float* wq  = (const float*)d_in[1];
    const float* bq  = (const float*)d_in[2];
    const float* wk  = (const float*)d_in[3];
    const float* bk  = (const float*)d_in[4];
    const float* wv  = (const float*)d_in[5];
    const float* bv  = (const float*)d_in[6];
    const float* wo  = (const float*)d_in[7];
    const float* bo  = (const float*)d_in[8];
    const float* g1  = (const float*)d_in[9];
    const float* be1 = (const float*)d_in[10];
    const float* w1  = (const float*)d_in[11];
    const float* b1  = (const float*)d_in[12];
    const float* w2  = (const float*)d_in[13];
    const float* b2  = (const float*)d_in[14];
    const float* g2  = (const float*)d_in[15];
    const float* be2 = (const float*)d_in[16];

    char* base = (char*)d_ws;
    unsigned short* Qb  = (unsigned short*)base;                  // 1 MB
    unsigned short* Kb  = (unsigned short*)(base + (1u << 20));   // 1 MB
    unsigned short* Vtg = (unsigned short*)(base + (2u << 20));   // 1 MB
    float*          P   = (float*)(base + (3u << 20));            // 5.9 MB
    float4*         wo4 = (float4*)(base + (9u << 20));           // 16 KB
    float4*         w14 = (float4*)(base + (9u << 20) + 0x10000); // 64 KB
    float4*         w24 = (float4*)(base + (9u << 20) + 0x20000); // 64 KB

    k_qkv      <<<T / 32, 256, 0, stream>>>(x, wq, bq, wk, bk, wv, bv,
                                            wo, w1, w2, Qb, Kb, Vtg,
                                            wo4, w14, w24);
    k_attn_part<<<NZ, 256, 0, stream>>>(Qb, Kb, Vtg, P);
    k_post     <<<T / 16, 512, 0, stream>>>(P, x, wo4, bo, g1, be1,
                                            w14, b1, w24, b2, g2, be2,
                                            (float*)d_out);
}